// Round 16
// baseline (1025.810 us; speedup 1.0000x reference)
//
#include <hip/hip_runtime.h>
#include <hip/hip_bf16.h>
#include <math.h>
#include <stdint.h>

#define TOK 32768
#define DIM 1024
#define NE 8
#define NSEG 16                      /* (k, expert) segments */
#define BMCAP (2 * TOK + NSEG * 128) /* 67584 row slots */
#define RCAP (TOK + NE * 128)        /* 33792 rows per k-region cap */
#define MT_R (RCAP / 128)            /* 264 m-tiles per region */

#define C_CNT(s) ((s) * 16)
#define C_CUR(s) (256 + (s) * 16)
#define C_SEG(s) (512 + (s))

typedef __attribute__((ext_vector_type(8))) short bf16x8;
typedef __attribute__((ext_vector_type(4))) float f32x4;
typedef unsigned short ushort_t;

#define VMCNT(n) asm volatile("s_waitcnt vmcnt(" #n ")" ::: "memory")
__device__ __forceinline__ void barrier_raw() {
  __builtin_amdgcn_sched_barrier(0);
  __builtin_amdgcn_s_barrier();
  __builtin_amdgcn_sched_barrier(0);
}

__device__ __forceinline__ unsigned short f2b(float x) {
  union { float f; unsigned u; } v; v.f = x;
  unsigned r = v.u + 0x7fffu + ((v.u >> 16) & 1u);
  return (unsigned short)(r >> 16);
}

__device__ __forceinline__ void async16(void* lds, const void* g) {
  auto* lp = (__attribute__((address_space(3))) uint32_t*)lds;
  auto* gp = (__attribute__((address_space(1))) uint32_t*)(const_cast<void*>(g));
  __builtin_amdgcn_global_load_lds(gp, lp, 16, 0, 0);
}

// ---- router v3 (no atomics): FROZEN sequential fmaf chain ------------------
__global__ __launch_bounds__(256) void router_seq3(
    const float* __restrict__ tokens, const float* __restrict__ rw,
    int* __restrict__ topi, float* __restrict__ topv) {
  __shared__ float xs[2][32][132];
  __shared__ float wsh[2][8][132];
  __shared__ float sc[256];
  const int tid = threadIdx.x;
  const int e = tid & 7;
  const int tr = tid >> 3;
  const int t0 = blockIdx.x * 32;

  float4 lx0, lx1, lx2, lx3, lw;
  auto issue = [&](int c) {
    const int col = (tid & 31) * 4;
    lx0 = *(const float4*)&tokens[(size_t)(t0 + ((tid + 0) >> 5)) * DIM + c * 128 + col];
    lx1 = *(const float4*)&tokens[(size_t)(t0 + ((tid + 256) >> 5)) * DIM + c * 128 + col];
    lx2 = *(const float4*)&tokens[(size_t)(t0 + ((tid + 512) >> 5)) * DIM + c * 128 + col];
    lx3 = *(const float4*)&tokens[(size_t)(t0 + ((tid + 768) >> 5)) * DIM + c * 128 + col];
    lw  = *(const float4*)&rw[(size_t)(tid >> 5) * DIM + c * 128 + col];
  };
  auto commit = [&](int b) {
    const int col = (tid & 31) * 4;
    *(float4*)&xs[b][(tid + 0) >> 5][col] = lx0;
    *(float4*)&xs[b][(tid + 256) >> 5][col] = lx1;
    *(float4*)&xs[b][(tid + 512) >> 5][col] = lx2;
    *(float4*)&xs[b][(tid + 768) >> 5][col] = lx3;
    *(float4*)&wsh[b][tid >> 5][col] = lw;
  };

  issue(0);
  commit(0);
  __syncthreads();
  float s = 0.f;
  for (int c = 0; c < 8; c++) {
    const int b = c & 1;
    if (c + 1 < 8) issue(c + 1);
#pragma unroll
    for (int k4 = 0; k4 < 32; k4++) {
      const float4 xv = *(const float4*)&xs[b][tr][k4 * 4];
      const float4 wv = *(const float4*)&wsh[b][e][k4 * 4];
      s = fmaf(xv.x, wv.x, s);
      s = fmaf(xv.y, wv.y, s);
      s = fmaf(xv.z, wv.z, s);
      s = fmaf(xv.w, wv.w, s);
    }
    if (c + 1 < 8) commit(b ^ 1);
    __syncthreads();
  }
  sc[tid] = s;
  __syncthreads();
  if (e == 0) {
    float p[NE];
    float m = sc[tr * 8];
#pragma unroll
    for (int i = 1; i < NE; i++) m = fmaxf(m, sc[tr * 8 + i]);
    float sum = 0.f;
#pragma unroll
    for (int i = 0; i < NE; i++) {
      p[i] = expf(sc[tr * 8 + i] - m);
      sum += p[i];
    }
#pragma unroll
    for (int i = 0; i < NE; i++) p[i] = p[i] / sum;
    const int t = t0 + tr;
    int e0 = 0;
#pragma unroll
    for (int i = 1; i < NE; i++) if (p[i] > p[e0]) e0 = i;
    int e1 = (e0 == 0) ? 1 : 0;
#pragma unroll
    for (int i = 0; i < NE; i++) if (i != e0 && p[i] > p[e1]) e1 = i;
    topi[t * 2] = e0;     topv[t * 2] = p[e0];
    topi[t * 2 + 1] = e1; topv[t * 2 + 1] = p[e1];
  }
}

// ---- per-(k,expert) counts -------------------------------------------------
__global__ __launch_bounds__(256) void hist_kernel(const int* __restrict__ topi,
                                                   int* __restrict__ ctrl) {
  __shared__ int h[NSEG];
  const int tid = threadIdx.x;
  if (tid < NSEG) h[tid] = 0;
  __syncthreads();
  const int t = blockIdx.x * 256 + tid;
  atomicAdd(&h[topi[t * 2]], 1);
  atomicAdd(&h[8 + topi[t * 2 + 1]], 1);
  __syncthreads();
  if (tid < NSEG) atomicAdd(&ctrl[C_CNT(tid)], h[tid]);
}

__global__ void prefix_kernel(int* ctrl) {
  if (threadIdx.x == 0 && blockIdx.x == 0) {
    int s = 0;
    for (int g = 0; g < NSEG; g++) {
      ctrl[C_SEG(g)] = s;
      ctrl[C_CUR(g)] = s;
      s += (ctrl[C_CNT(g)] + 127) & ~127;
    }
    ctrl[C_SEG(NSEG)] = s;
  }
}

__global__ __launch_bounds__(256) void init_rows(
    int* __restrict__ row_token, float* __restrict__ row_gate) {
  const int i = blockIdx.x * 256 + threadIdx.x;
  if (i < BMCAP) { row_token[i] = TOK; row_gate[i] = 0.f; }
}

__global__ __launch_bounds__(256) void assign2(
    const int* __restrict__ topi, const float* __restrict__ topv,
    int* __restrict__ ctrl, int* __restrict__ row_token,
    float* __restrict__ row_gate) {
  __shared__ int h[NSEG];
  __shared__ int base[NSEG];
  const int tid = threadIdx.x;
  const int t = blockIdx.x * 256 + tid;
  if (tid < NSEG) h[tid] = 0;
  __syncthreads();
  const int s0 = topi[t * 2], s1 = 8 + topi[t * 2 + 1];
  const int o0 = atomicAdd(&h[s0], 1);
  const int o1 = atomicAdd(&h[s1], 1);
  __syncthreads();
  if (tid < NSEG) base[tid] = atomicAdd(&ctrl[C_CUR(tid)], h[tid]);
  __syncthreads();
  const int p0 = base[s0] + o0, p1 = base[s1] + o1;
  row_token[p0] = t; row_gate[p0] = topv[t * 2];
  row_token[p1] = t; row_gate[p1] = topv[t * 2 + 1];
}

__global__ __launch_bounds__(256) void cast_tokens(
    const float* __restrict__ t, ushort_t* __restrict__ x16) {
  const size_t i = ((size_t)blockIdx.x * 256 + threadIdx.x) * 8;
  const float4 a = *(const float4*)(t + i);
  const float4 b = *(const float4*)(t + i + 4);
  bf16x8 h;
  h[0] = (short)f2b(a.x); h[1] = (short)f2b(a.y);
  h[2] = (short)f2b(a.z); h[3] = (short)f2b(a.w);
  h[4] = (short)f2b(b.x); h[5] = (short)f2b(b.y);
  h[6] = (short)f2b(b.z); h[7] = (short)f2b(b.w);
  *(bf16x8*)(x16 + i) = h;
}

__global__ __launch_bounds__(256) void transpose_cast(
    const float* __restrict__ w, ushort_t* __restrict__ wT) {
  __shared__ float tile[64][65];
  const int e = blockIdx.z;
  const int n0 = blockIdx.x * 64, k0 = blockIdx.y * 64;
  const int tx = threadIdx.x & 63, ty = threadIdx.x >> 6;
  const float* src = w + ((size_t)e << 20);
  ushort_t* dst = wT + ((size_t)e << 20);
#pragma unroll
  for (int r = ty; r < 64; r += 4)
    tile[r][tx] = src[(size_t)(k0 + r) * DIM + n0 + tx];
  __syncthreads();
#pragma unroll
  for (int r = ty; r < 64; r += 4)
    dst[(size_t)(n0 + r) * DIM + k0 + tx] = f2b(tile[tx][r]);
}

// --- grouped GEMM: 128x128, BK=64, 4 waves, 3-buffer COUNTED-VMCNT pipe -----
// stage(s+2) -> vmcnt(16) -> s_barrier -> compute(s) -> s_barrier
// (each wave waits only its own oldest 8 loads; barrier makes it collective)
template <int PASS, int ADD>
__global__ __launch_bounds__(256, 1) void dgemm(
    const ushort_t* __restrict__ Asrc, const ushort_t* __restrict__ Wt,
    const int* __restrict__ row_token, const float* __restrict__ row_gate,
    const int* __restrict__ ctrl, int kreg, ushort_t* __restrict__ Hout,
    float* __restrict__ out) {
  const int l = (blockIdx.x & 7) * MT_R + (blockIdx.x >> 3); // 2112 = 8*264
  const int mt = l >> 3, nt = l & 7;
  const int rbase0 = ctrl[C_SEG(kreg * 8)];
  const int rend = ctrl[C_SEG(kreg * 8 + 8)];
  const int m0 = rbase0 + mt * 128;
  if (m0 >= rend) return;
  const int m0loc = m0 - rbase0;
  const int n0 = nt * 128;
  int e = 0;
#pragma unroll
  for (int i = 0; i < NE - 1; i++)
    if (m0 >= ctrl[C_SEG(kreg * 8 + i + 1)]) e = i + 1;
  const ushort_t* B = Wt + ((size_t)e << 20);

  __shared__ __align__(16) char smem[98304]; // 3x16KB A + 3x16KB B
  ushort_t (*As)[8192] = (ushort_t(*)[8192])smem;
  ushort_t (*Bs)[8192] = (ushort_t(*)[8192])(smem + 49152);
  float* scratch = (float*)smem; // epilogue: 4 waves x 16 KB

  const int tid = threadIdx.x;
  const int lane = tid & 63;
  const int wave = tid >> 6;
  const int wm = wave >> 1, wn = wave & 1; // per-wave 64x64 output
  const int lr = lane & 15;
  const int lk = (lane >> 4) << 3;
  const int sx = (lr & 7) << 3;

  const int srow = tid >> 3; /* 0..31 */
  const int ko = (((tid & 7) ^ (srow & 7)) << 3); // pre-swizzled source col
  const ushort_t* asrc[4];
  const ushort_t* bsrc[4];
#pragma unroll
  for (int j = 0; j < 4; j++) {
    const int rA = j * 32 + srow;
    if (PASS == 0) {
      int tk = row_token[m0 + rA];
      if (tk >= TOK) tk = 0;
      asrc[j] = Asrc + (size_t)tk * DIM + ko;
    } else {
      asrc[j] = Asrc + (size_t)(m0loc + rA) * DIM + ko;
    }
    bsrc[j] = B + (size_t)(n0 + rA) * DIM + ko;
  }
  const int ldst = (tid & ~63) * 8; // wave-uniform base (HW adds lane*16B)

  f32x4 acc[4][4] = {};

  auto stage = [&](int b, int k0) { // 8 wave-level gload_lds
#pragma unroll
    for (int j = 0; j < 4; j++) async16(&As[b][j * 2048 + ldst], asrc[j] + k0);
#pragma unroll
    for (int j = 0; j < 4; j++) async16(&Bs[b][j * 2048 + ldst], bsrc[j] + k0);
  };
  auto compute = [&](int b) {
    __builtin_amdgcn_s_setprio(1);
#pragma unroll
    for (int kk = 0; kk < 2; kk++) {
      const int kc = (kk * 32 + lk) ^ sx;
      bf16x8 a[4], bb[4];
#pragma unroll
      for (int i = 0; i < 4; i++)
        a[i] = *(const bf16x8*)&As[b][(wm * 64 + i * 16 + lr) * 64 + kc];
#pragma unroll
      for (int i = 0; i < 4; i++)
        bb[i] = *(const bf16x8*)&Bs[b][(wn * 64 + i * 16 + lr) * 64 + kc];
#pragma unroll
      for (int mi = 0; mi < 4; mi++)
#pragma unroll
        for (int ni = 0; ni < 4; ni++)
          acc[mi][ni] = __builtin_amdgcn_mfma_f32_16x16x32_bf16(
              a[mi], bb[ni], acc[mi][ni], 0, 0, 0);
    }
    __builtin_amdgcn_s_setprio(0);
  };

  stage(0, 0);
  stage(1, 64);
#pragma unroll 1
  for (int s = 0; s < 14; s++) {
    stage((s + 2) % 3, (s + 2) * 64);
    VMCNT(16); // wait only K-step s's 8 loads (16 younger stay in flight)
    barrier_raw();
    compute(s % 3);
    barrier_raw();
  }
  VMCNT(8);
  barrier_raw();
  compute(2); // s=14
  barrier_raw();
  VMCNT(0);
  barrier_raw();
  compute(0); // s=15
  __syncthreads(); // before scratch reuse

  // ---- LDS-transpose epilogue: per-wave 64x64 f32 window ------------------
  const int grow = (lane >> 4) << 2;
  float* sw = scratch + wave * 4096;
#pragma unroll
  for (int mi = 0; mi < 4; mi++) {
#pragma unroll
    for (int ni = 0; ni < 4; ni++) {
#pragma unroll
      for (int r = 0; r < 4; r++) {
        const int lrow = mi * 16 + grow + r;
        const int lcol = (ni * 16 + lr) ^ (((lrow >> 2) & 3) << 4);
        sw[lrow * 64 + lcol] = acc[mi][ni][r];
      }
    }
  }
  if (PASS == 0) {
#pragma unroll
    for (int i = 0; i < 8; i++) {
      const int lrow = i * 8 + (lane >> 3);
      const int q = ((lrow >> 2) & 3) << 4;
      const int c0 = (lane & 7) * 8;
      const f32x4 v0 = *(const f32x4*)&sw[lrow * 64 + (c0 ^ q)];
      const f32x4 v1 = *(const f32x4*)&sw[lrow * 64 + ((c0 + 4) ^ q)];
      bf16x8 h;
#pragma unroll
      for (int j = 0; j < 4; j++) {
        const float x = v0[j];
        h[j] = (short)f2b(0.5f * x * (1.f + erff(x * 0.70710678118654752f)));
      }
#pragma unroll
      for (int j = 0; j < 4; j++) {
        const float x = v1[j];
        h[4 + j] =
            (short)f2b(0.5f * x * (1.f + erff(x * 0.70710678118654752f)));
      }
      const int rloc = m0loc + wm * 64 + lrow;
      *(bf16x8*)&Hout[(size_t)rloc * DIM + n0 + wn * 64 + c0] = h;
    }
  } else {
#pragma unroll
    for (int i = 0; i < 16; i++) {
      const int lrow = i * 4 + (lane >> 4);
      const int q = ((lrow >> 2) & 3) << 4;
      const int c0 = (lane & 15) * 4;
      const f32x4 v = *(const f32x4*)&sw[lrow * 64 + ((c0 ^ q))];
      const int rr = m0 + wm * 64 + lrow;
      const int tok = row_token[rr];
      if (tok < TOK) {
        const float g = row_gate[rr];
        float* op = out + (size_t)tok * DIM + n0 + wn * 64 + c0;
        f32x4 res;
        if (ADD) {
          const f32x4 old = *(const f32x4*)op;
#pragma unroll
          for (int j = 0; j < 4; j++) res[j] = old[j] + g * v[j];
        } else {
#pragma unroll
          for (int j = 0; j < 4; j++) res[j] = g * v[j];
        }
        *(f32x4*)op = res;
      }
    }
  }
}

// ==== diagnostics (floors; write checksums to scratch) ======================
__global__ __launch_bounds__(256, 1) void diag_stage(
    const ushort_t* __restrict__ Asrc, const ushort_t* __restrict__ B,
    float* __restrict__ diag) {
  const int l = (blockIdx.x & 7) * 256 + (blockIdx.x >> 3);
  const int mt = l >> 3, nt = l & 7;
  __shared__ __align__(16) char smem[98304];
  ushort_t (*As)[8192] = (ushort_t(*)[8192])smem;
  ushort_t (*Bs)[8192] = (ushort_t(*)[8192])(smem + 49152);
  const int tid = threadIdx.x;
  const int srow = tid >> 3;
  const int ko = (((tid & 7) ^ (srow & 7)) << 3);
  const ushort_t* asrc[4];
  const ushort_t* bsrc[4];
#pragma unroll
  for (int j = 0; j < 4; j++) {
    asrc[j] = Asrc + (size_t)(mt * 128 + j * 32 + srow) * DIM + ko;
    bsrc[j] = B + (size_t)(nt * 128 + j * 32 + srow) * DIM + ko;
  }
  const int ldst = (tid & ~63) * 8;
  auto stage = [&](int b, int k0) {
#pragma unroll
    for (int j = 0; j < 4; j++) async16(&As[b][j * 2048 + ldst], asrc[j] + k0);
#pragma unroll
    for (int j = 0; j < 4; j++) async16(&Bs[b][j * 2048 + ldst], bsrc[j] + k0);
  };
  stage(0, 0);
  stage(1, 64);
#pragma unroll 1
  for (int s = 0; s < 14; s++) {
    stage((s + 2) % 3, (s + 2) * 64);
    VMCNT(16);
    barrier_raw();
    barrier_raw();
  }
  VMCNT(0);
  barrier_raw();
  diag[(size_t)blockIdx.x * 256 + tid] =
      (float)As[0][tid] + (float)Bs[0][tid];
}

__global__ __launch_bounds__(256, 1) void diag_mfma(
    const ushort_t* __restrict__ Asrc, const ushort_t* __restrict__ B,
    float* __restrict__ diag) {
  const int l = (blockIdx.x & 7) * 256 + (blockIdx.x >> 3);
  const int mt = l >> 3, nt = l & 7;
  __shared__ __align__(16) char smem[98304];
  ushort_t (*As)[8192] = (ushort_t(*)[8192])smem;
  ushort_t (*Bs)[8192] = (ushort_t(*)[8192])(smem + 49152);
  const int tid = threadIdx.x;
  const int lane = tid & 63;
  const int wave = tid >> 6;
  const int wm = wave >> 1, wn = wave & 1;
  const int lr = lane & 15;
  const int lk = (lane >> 4) << 3;
  const int sx = (lr & 7) << 3;
  const int srow = tid >> 3;
  const int ko = (((tid & 7) ^ (srow & 7)) << 3);
  const int ldst = (tid & ~63) * 8;
#pragma unroll
  for (int j = 0; j < 4; j++) {
    async16(&As[0][j * 2048 + ldst],
            Asrc + (size_t)(mt * 128 + j * 32 + srow) * DIM + ko);
    async16(&Bs[0][j * 2048 + ldst],
            B + (size_t)(nt * 128 + j * 32 + srow) * DIM + ko);
  }
  VMCNT(0);
  barrier_raw();
  f32x4 acc[4][4] = {};
#pragma unroll 1
  for (int s = 0; s < 16; s++) {
    barrier_raw();
#pragma unroll
    for (int kk = 0; kk < 2; kk++) {
      const int kc = (kk * 32 + lk) ^ sx;
      bf16x8 a[4], bb[4];
#pragma unroll
      for (int i = 0; i < 4; i++)
        a[i] = *(const bf16x8*)&As[0][(wm * 64 + i * 16 + lr) * 64 + kc];
#pragma unroll
      for (int i = 0; i < 4; i++)
        bb[i] = *(const bf16x8*)&Bs[0][(wn * 64 + i * 16 + lr) * 64 + kc];
#pragma unroll
      for (int mi = 0; mi < 4; mi++)
#pragma unroll
        for (int ni = 0; ni < 4; ni++)
          acc[mi][ni] = __builtin_amdgcn_mfma_f32_16x16x32_bf16(
              a[mi], bb[ni], acc[mi][ni], 0, 0, 0);
    }
    barrier_raw();
  }
  float cs = 0.f;
#pragma unroll
  for (int mi = 0; mi < 4; mi++)
#pragma unroll
    for (int ni = 0; ni < 4; ni++)
#pragma unroll
      for (int r = 0; r < 4; r++) cs += acc[mi][ni][r];
  diag[(size_t)blockIdx.x * 256 + tid] = cs;
}

extern "C" void kernel_launch(void* const* d_in, const int* in_sizes, int n_in,
                              void* d_out, int out_size, void* d_ws,
                              size_t ws_size, hipStream_t stream) {
  (void)in_sizes; (void)n_in; (void)ws_size; (void)out_size;
  const float* tokens = (const float*)d_in[0];
  const float* rw = (const float*)d_in[1];
  const float* w1 = (const float*)d_in[2];
  const float* w2 = (const float*)d_in[3];
  float* out = (float*)d_out;

  char* ws = (char*)d_ws;
  size_t off = 0;
  auto alloc = [&](size_t b) {
    size_t o = off;
    off += (b + 255) & ~(size_t)255;
    return o;
  };
  int* ctrl = (int*)(ws + alloc(4096));
  int* topi = (int*)(ws + alloc((size_t)TOK * 2 * 4));
  float* topv = (float*)(ws + alloc((size_t)TOK * 2 * 4));
  int* row_token = (int*)(ws + alloc((size_t)BMCAP * 4));
  float* row_gate = (float*)(ws + alloc((size_t)BMCAP * 4));
  ushort_t* X16 = (ushort_t*)(ws + alloc((size_t)TOK * DIM * 2));
  ushort_t* w1T = (ushort_t*)(ws + alloc((size_t)NE * DIM * DIM * 2));
  ushort_t* w2T = (ushort_t*)(ws + alloc((size_t)NE * DIM * DIM * 2));
  ushort_t* H = (ushort_t*)(ws + alloc((size_t)RCAP * DIM * 2));
  float* diagb = (float*)(ws + alloc((size_t)2048 * 256 * 4));

  hipMemsetAsync(ctrl, 0, 4096, stream);
  router_seq3<<<TOK / 32, 256, 0, stream>>>(tokens, rw, topi, topv);
  hist_kernel<<<TOK / 256, 256, 0, stream>>>(topi, ctrl);
  prefix_kernel<<<1, 64, 0, stream>>>(ctrl);
  init_rows<<<BMCAP / 256, 256, 0, stream>>>(row_token, row_gate);
  assign2<<<TOK / 256, 256, 0, stream>>>(topi, topv, ctrl, row_token,
                                         row_gate);
  cast_tokens<<<TOK * DIM / 8 / 256, 256, 0, stream>>>(tokens, X16);
  dim3 tg(16, 16, 8);
  transpose_cast<<<tg, 256, 0, stream>>>(w1, w1T);
  transpose_cast<<<tg, 256, 0, stream>>>(w2, w2T);
  dgemm<0, 0><<<MT_R * 8, 256, 0, stream>>>(X16, w1T, row_token, row_gate,
                                            ctrl, 0, H, out);
  dgemm<1, 0><<<MT_R * 8, 256, 0, stream>>>(H, w2T, row_token, row_gate, ctrl,
                                            0, H, out);
  dgemm<0, 0><<<MT_R * 8, 256, 0, stream>>>(X16, w1T, row_token, row_gate,
                                            ctrl, 1, H, out);
  dgemm<1, 1><<<MT_R * 8, 256, 0, stream>>>(H, w2T, row_token, row_gate, ctrl,
                                            1, H, out);
  // diagnostics (floors; removed next round)
  diag_stage<<<2048, 256, 0, stream>>>(X16, w1T, diagb);
  diag_mfma<<<2048, 256, 0, stream>>>(X16, w1T, diagb);
}

// Round 17
// 730.398 us; speedup vs baseline: 1.4045x; 1.4045x over previous
//
#include <hip/hip_runtime.h>
#include <hip/hip_bf16.h>
#include <math.h>
#include <stdint.h>

#define TOK 32768
#define DIM 1024
#define NE 8
#define NSEG 16                      /* (k, expert) segments */
#define BMCAP (2 * TOK + NSEG * 256) /* 69632 row slots (segments padded to 256) */
#define RCAP (TOK + NE * 256)        /* 34816 rows per k-region cap */
#define MT_R (RCAP / 256)            /* 136 m-tiles per region */

#define C_CNT(s) ((s) * 16)
#define C_CUR(s) (256 + (s) * 16)
#define C_SEG(s) (512 + (s))

typedef __attribute__((ext_vector_type(8))) short bf16x8;
typedef __attribute__((ext_vector_type(4))) float f32x4;
typedef unsigned short ushort_t;

#define VMCNT(n) asm volatile("s_waitcnt vmcnt(" #n ")" ::: "memory")
__device__ __forceinline__ void barrier_raw() {
  __builtin_amdgcn_sched_barrier(0);
  __builtin_amdgcn_s_barrier();
  __builtin_amdgcn_sched_barrier(0);
}

__device__ __forceinline__ unsigned short f2b(float x) {
  union { float f; unsigned u; } v; v.f = x;
  unsigned r = v.u + 0x7fffu + ((v.u >> 16) & 1u);
  return (unsigned short)(r >> 16);
}

__device__ __forceinline__ void async16(void* lds, const void* g) {
  auto* lp = (__attribute__((address_space(3))) uint32_t*)lds;
  auto* gp = (__attribute__((address_space(1))) uint32_t*)(const_cast<void*>(g));
  __builtin_amdgcn_global_load_lds(gp, lp, 16, 0, 0);
}

// ---- router v3 (no atomics): FROZEN sequential fmaf chain ------------------
__global__ __launch_bounds__(256) void router_seq3(
    const float* __restrict__ tokens, const float* __restrict__ rw,
    int* __restrict__ topi, float* __restrict__ topv) {
  __shared__ float xs[2][32][132];
  __shared__ float wsh[2][8][132];
  __shared__ float sc[256];
  const int tid = threadIdx.x;
  const int e = tid & 7;
  const int tr = tid >> 3;
  const int t0 = blockIdx.x * 32;

  float4 lx0, lx1, lx2, lx3, lw;
  auto issue = [&](int c) {
    const int col = (tid & 31) * 4;
    lx0 = *(const float4*)&tokens[(size_t)(t0 + ((tid + 0) >> 5)) * DIM + c * 128 + col];
    lx1 = *(const float4*)&tokens[(size_t)(t0 + ((tid + 256) >> 5)) * DIM + c * 128 + col];
    lx2 = *(const float4*)&tokens[(size_t)(t0 + ((tid + 512) >> 5)) * DIM + c * 128 + col];
    lx3 = *(const float4*)&tokens[(size_t)(t0 + ((tid + 768) >> 5)) * DIM + c * 128 + col];
    lw  = *(const float4*)&rw[(size_t)(tid >> 5) * DIM + c * 128 + col];
  };
  auto commit = [&](int b) {
    const int col = (tid & 31) * 4;
    *(float4*)&xs[b][(tid + 0) >> 5][col] = lx0;
    *(float4*)&xs[b][(tid + 256) >> 5][col] = lx1;
    *(float4*)&xs[b][(tid + 512) >> 5][col] = lx2;
    *(float4*)&xs[b][(tid + 768) >> 5][col] = lx3;
    *(float4*)&wsh[b][tid >> 5][col] = lw;
  };

  issue(0);
  commit(0);
  __syncthreads();
  float s = 0.f;
  for (int c = 0; c < 8; c++) {
    const int b = c & 1;
    if (c + 1 < 8) issue(c + 1);
#pragma unroll
    for (int k4 = 0; k4 < 32; k4++) {
      const float4 xv = *(const float4*)&xs[b][tr][k4 * 4];
      const float4 wv = *(const float4*)&wsh[b][e][k4 * 4];
      s = fmaf(xv.x, wv.x, s);
      s = fmaf(xv.y, wv.y, s);
      s = fmaf(xv.z, wv.z, s);
      s = fmaf(xv.w, wv.w, s);
    }
    if (c + 1 < 8) commit(b ^ 1);
    __syncthreads();
  }
  sc[tid] = s;
  __syncthreads();
  if (e == 0) {
    float p[NE];
    float m = sc[tr * 8];
#pragma unroll
    for (int i = 1; i < NE; i++) m = fmaxf(m, sc[tr * 8 + i]);
    float sum = 0.f;
#pragma unroll
    for (int i = 0; i < NE; i++) {
      p[i] = expf(sc[tr * 8 + i] - m);
      sum += p[i];
    }
#pragma unroll
    for (int i = 0; i < NE; i++) p[i] = p[i] / sum;
    const int t = t0 + tr;
    int e0 = 0;
#pragma unroll
    for (int i = 1; i < NE; i++) if (p[i] > p[e0]) e0 = i;
    int e1 = (e0 == 0) ? 1 : 0;
#pragma unroll
    for (int i = 0; i < NE; i++) if (i != e0 && p[i] > p[e1]) e1 = i;
    topi[t * 2] = e0;     topv[t * 2] = p[e0];
    topi[t * 2 + 1] = e1; topv[t * 2 + 1] = p[e1];
  }
}

// ---- per-(k,expert) counts -------------------------------------------------
__global__ __launch_bounds__(256) void hist_kernel(const int* __restrict__ topi,
                                                   int* __restrict__ ctrl) {
  __shared__ int h[NSEG];
  const int tid = threadIdx.x;
  if (tid < NSEG) h[tid] = 0;
  __syncthreads();
  const int t = blockIdx.x * 256 + tid;
  atomicAdd(&h[topi[t * 2]], 1);
  atomicAdd(&h[8 + topi[t * 2 + 1]], 1);
  __syncthreads();
  if (tid < NSEG) atomicAdd(&ctrl[C_CNT(tid)], h[tid]);
}

__global__ void prefix_kernel(int* ctrl) {
  if (threadIdx.x == 0 && blockIdx.x == 0) {
    int s = 0;
    for (int g = 0; g < NSEG; g++) {
      ctrl[C_SEG(g)] = s;
      ctrl[C_CUR(g)] = s;
      s += (ctrl[C_CNT(g)] + 255) & ~255; /* pad segments to 256 (BM) */
    }
    ctrl[C_SEG(NSEG)] = s;
  }
}

__global__ __launch_bounds__(256) void init_rows(
    int* __restrict__ row_token, float* __restrict__ row_gate) {
  const int i = blockIdx.x * 256 + threadIdx.x;
  if (i < BMCAP) { row_token[i] = TOK; row_gate[i] = 0.f; }
}

__global__ __launch_bounds__(256) void assign2(
    const int* __restrict__ topi, const float* __restrict__ topv,
    int* __restrict__ ctrl, int* __restrict__ row_token,
    float* __restrict__ row_gate) {
  __shared__ int h[NSEG];
  __shared__ int base[NSEG];
  const int tid = threadIdx.x;
  const int t = blockIdx.x * 256 + tid;
  if (tid < NSEG) h[tid] = 0;
  __syncthreads();
  const int s0 = topi[t * 2], s1 = 8 + topi[t * 2 + 1];
  const int o0 = atomicAdd(&h[s0], 1);
  const int o1 = atomicAdd(&h[s1], 1);
  __syncthreads();
  if (tid < NSEG) base[tid] = atomicAdd(&ctrl[C_CUR(tid)], h[tid]);
  __syncthreads();
  const int p0 = base[s0] + o0, p1 = base[s1] + o1;
  row_token[p0] = t; row_gate[p0] = topv[t * 2];
  row_token[p1] = t; row_gate[p1] = topv[t * 2 + 1];
}

__global__ __launch_bounds__(256) void cast_tokens(
    const float* __restrict__ t, ushort_t* __restrict__ x16) {
  const size_t i = ((size_t)blockIdx.x * 256 + threadIdx.x) * 8;
  const float4 a = *(const float4*)(t + i);
  const float4 b = *(const float4*)(t + i + 4);
  bf16x8 h;
  h[0] = (short)f2b(a.x); h[1] = (short)f2b(a.y);
  h[2] = (short)f2b(a.z); h[3] = (short)f2b(a.w);
  h[4] = (short)f2b(b.x); h[5] = (short)f2b(b.y);
  h[6] = (short)f2b(b.z); h[7] = (short)f2b(b.w);
  *(bf16x8*)(x16 + i) = h;
}

__global__ __launch_bounds__(256) void transpose_cast(
    const float* __restrict__ w, ushort_t* __restrict__ wT) {
  __shared__ float tile[64][65];
  const int e = blockIdx.z;
  const int n0 = blockIdx.x * 64, k0 = blockIdx.y * 64;
  const int tx = threadIdx.x & 63, ty = threadIdx.x >> 6;
  const float* src = w + ((size_t)e << 20);
  ushort_t* dst = wT + ((size_t)e << 20);
#pragma unroll
  for (int r = ty; r < 64; r += 4)
    tile[r][tx] = src[(size_t)(k0 + r) * DIM + n0 + tx];
  __syncthreads();
#pragma unroll
  for (int r = ty; r < 64; r += 4)
    dst[(size_t)(n0 + r) * DIM + k0 + tx] = f2b(tile[tx][r]);
}

// ---- grouped GEMM: 256x256, 8 waves, BK=32, 4-buffer ring, counted vmcnt ---
// Phase template (adapted m201): per half-iteration
//   VMCNT(4) -> s_barrier -> {STAGE op (2 gload_lds) ; 16 MFMA (setprio)} x2
// Stage-ahead = 2 K-tiles; uniform vmcnt(4) gates (in-order retirement);
// 16B-granule XOR swizzle both-sides; wide-store LDS-transpose epilogue.
template <int PASS, int ADD>
__global__ __launch_bounds__(512, 1) void dgemm(
    const ushort_t* __restrict__ Asrc, const ushort_t* __restrict__ Wt,
    const int* __restrict__ row_token, const float* __restrict__ row_gate,
    const int* __restrict__ ctrl, int kreg, ushort_t* __restrict__ Hout,
    float* __restrict__ out) {
  const int l = (blockIdx.x & 7) * (MT_R / 2) + (blockIdx.x >> 3); // 544=8*68
  const int mt = l >> 2, nt = l & 3;
  const int rbase0 = ctrl[C_SEG(kreg * 8)];
  const int rend = ctrl[C_SEG(kreg * 8 + 8)];
  const int m0 = rbase0 + mt * 256;
  if (m0 >= rend) return;
  const int m0loc = m0 - rbase0;
  const int n0 = nt * 256;
  int e = 0;
#pragma unroll
  for (int i = 0; i < NE - 1; i++)
    if (m0 >= ctrl[C_SEG(kreg * 8 + i + 1)]) e = i + 1;
  const ushort_t* B = Wt + ((size_t)e << 20);

  // ring: [tile&3][op A/B][2 halves x 128 rows x 32 cols] = 131072 B
  __shared__ ushort_t sbuf[4][2][8192];
  float* scratch = (float*)sbuf; // epilogue alias: 8 waves x 4096 f32

  const int tid = threadIdx.x;
  const int lane = tid & 63;
  const int wave = tid >> 6;
  const int wm = wave >> 2, wn = wave & 3; // per-wave 128x64 output
  const int lr = lane & 15;
  const int lk = (lane >> 4) << 3;
  const int kx = (lr & 3) << 3; // read-side swizzle XOR (elements)

  // staging: thread stages rows q*128 + (tid>>2), col-chunk tid&3 (16B),
  // source col pre-swizzled by row&3 (both-sides involution, rule #21)
  const int srow = tid >> 2;
  const int ko = (((tid & 3) ^ (srow & 3)) << 3);
  const ushort_t *a0, *a1, *b0, *b1;
  if (PASS == 0) {
    int tk0 = row_token[m0 + srow];
    int tk1 = row_token[m0 + 128 + srow];
    if (tk0 >= TOK) tk0 = 0;
    if (tk1 >= TOK) tk1 = 0;
    a0 = Asrc + (size_t)tk0 * DIM + ko;
    a1 = Asrc + (size_t)tk1 * DIM + ko;
  } else {
    a0 = Asrc + (size_t)(m0loc + srow) * DIM + ko;
    a1 = Asrc + (size_t)(m0loc + 128 + srow) * DIM + ko;
  }
  b0 = B + (size_t)(n0 + srow) * DIM + ko;
  b1 = B + (size_t)(n0 + 128 + srow) * DIM + ko;
  const int ldst = (tid & ~63) * 8; // wave-uniform elem base (HW adds lane*16B)

  f32x4 acc[8][4] = {};

  auto STAGE_A = [&](int t) {
    async16(&sbuf[t & 3][0][ldst], a0 + t * 32);
    async16(&sbuf[t & 3][0][4096 + ldst], a1 + t * 32);
  };
  auto STAGE_B = [&](int t) {
    async16(&sbuf[t & 3][1][ldst], b0 + t * 32);
    async16(&sbuf[t & 3][1][4096 + ldst], b1 + t * 32);
  };
  auto COMPUTE = [&](int t, int mh) {
    const ushort_t* As_ = sbuf[t & 3][0];
    const ushort_t* Bs_ = sbuf[t & 3][1];
    bf16x8 a[4], bb[4];
#pragma unroll
    for (int mi = 0; mi < 4; mi++)
      a[mi] = *(const bf16x8*)&As_[wm * 4096 +
                                   (mh * 64 + mi * 16 + lr) * 32 + (lk ^ kx)];
#pragma unroll
    for (int ni = 0; ni < 4; ni++)
      bb[ni] = *(const bf16x8*)&Bs_[(wn >> 1) * 4096 +
                                    ((wn & 1) * 64 + ni * 16 + lr) * 32 +
                                    (lk ^ kx)];
    __builtin_amdgcn_s_setprio(1);
#pragma unroll
    for (int mi = 0; mi < 4; mi++)
#pragma unroll
      for (int ni = 0; ni < 4; ni++)
        acc[mh * 4 + mi][ni] = __builtin_amdgcn_mfma_f32_16x16x32_bf16(
            a[mi], bb[ni], acc[mh * 4 + mi][ni], 0, 0, 0);
    __builtin_amdgcn_s_setprio(0);
  };

  // prologue: tiles 0,1 in flight (8 loads/thread)
  STAGE_A(0); STAGE_B(0); STAGE_A(1); STAGE_B(1);
#pragma unroll 1
  for (int i = 0; i < 15; i++) {
    VMCNT(4);        // gate tile 2i (older than the 4 outstanding)
    barrier_raw();
    STAGE_A(2 * i + 2);
    COMPUTE(2 * i, 0);
    STAGE_B(2 * i + 2);
    COMPUTE(2 * i, 1);
    VMCNT(4);        // gate tile 2i+1
    barrier_raw();
    STAGE_A(2 * i + 3);
    COMPUTE(2 * i + 1, 0);
    STAGE_B(2 * i + 3);
    COMPUTE(2 * i + 1, 1);
  }
  VMCNT(4);
  barrier_raw();
  COMPUTE(30, 0);
  COMPUTE(30, 1);
  VMCNT(0);
  barrier_raw();
  COMPUTE(31, 0);
  COMPUTE(31, 1);
  __syncthreads(); // all waves done with ring before scratch reuse

  // ---- LDS-transpose epilogue (r15-verified): per-wave 64x64 f32 window ---
  const int grow = (lane >> 4) << 2;
  float* sw = scratch + wave * 4096;
#pragma unroll
  for (int half = 0; half < 2; half++) {
#pragma unroll
    for (int mi2 = 0; mi2 < 4; mi2++) {
      const int mi = half * 4 + mi2;
#pragma unroll
      for (int ni = 0; ni < 4; ni++) {
#pragma unroll
        for (int r = 0; r < 4; r++) {
          const int lrow = mi2 * 16 + grow + r;
          const int lcol = (ni * 16 + lr) ^ (((lrow >> 2) & 3) << 4);
          sw[lrow * 64 + lcol] = acc[mi][ni][r];
        }
      }
    }
    if (PASS == 0) {
#pragma unroll
      for (int i = 0; i < 8; i++) {
        const int lrow = i * 8 + (lane >> 3);
        const int q = ((lrow >> 2) & 3) << 4;
        const int c0 = (lane & 7) * 8;
        const f32x4 v0 = *(const f32x4*)&sw[lrow * 64 + (c0 ^ q)];
        const f32x4 v1 = *(const f32x4*)&sw[lrow * 64 + ((c0 + 4) ^ q)];
        bf16x8 h;
#pragma unroll
        for (int j = 0; j < 4; j++) {
          const float x = v0[j];
          h[j] = (short)f2b(0.5f * x * (1.f + erff(x * 0.70710678118654752f)));
        }
#pragma unroll
        for (int j = 0; j < 4; j++) {
          const float x = v1[j];
          h[4 + j] =
              (short)f2b(0.5f * x * (1.f + erff(x * 0.70710678118654752f)));
        }
        const int rloc = m0loc + wm * 128 + half * 64 + lrow;
        *(bf16x8*)&Hout[(size_t)rloc * DIM + n0 + wn * 64 + c0] = h;
      }
    } else {
#pragma unroll
      for (int i = 0; i < 16; i++) {
        const int lrow = i * 4 + (lane >> 4);
        const int q = ((lrow >> 2) & 3) << 4;
        const int c0 = (lane & 15) * 4;
        const f32x4 v = *(const f32x4*)&sw[lrow * 64 + (c0 ^ q)];
        const int rr = m0 + wm * 128 + half * 64 + lrow;
        const int tok = row_token[rr];
        if (tok < TOK) {
          const float g = row_gate[rr];
          float* op = out + (size_t)tok * DIM + n0 + wn * 64 + c0;
          f32x4 res;
          if (ADD) {
            const f32x4 old = *(const f32x4*)op;
#pragma unroll
            for (int j = 0; j < 4; j++) res[j] = old[j] + g * v[j];
          } else {
#pragma unroll
            for (int j = 0; j < 4; j++) res[j] = g * v[j];
          }
          *(f32x4*)op = res;
        }
      }
    }
  }
}

extern "C" void kernel_launch(void* const* d_in, const int* in_sizes, int n_in,
                              void* d_out, int out_size, void* d_ws,
                              size_t ws_size, hipStream_t stream) {
  (void)in_sizes; (void)n_in; (void)ws_size; (void)out_size;
  const float* tokens = (const float*)d_in[0];
  const float* rw = (const float*)d_in[1];
  const float* w1 = (const float*)d_in[2];
  const float* w2 = (const float*)d_in[3];
  float* out = (float*)d_out;

  char* ws = (char*)d_ws;
  size_t off = 0;
  auto alloc = [&](size_t b) {
    size_t o = off;
    off += (b + 255) & ~(size_t)255;
    return o;
  };
  int* ctrl = (int*)(ws + alloc(4096));
  int* topi = (int*)(ws + alloc((size_t)TOK * 2 * 4));
  float* topv = (float*)(ws + alloc((size_t)TOK * 2 * 4));
  int* row_token = (int*)(ws + alloc((size_t)BMCAP * 4));
  float* row_gate = (float*)(ws + alloc((size_t)BMCAP * 4));
  ushort_t* X16 = (ushort_t*)(ws + alloc((size_t)TOK * DIM * 2));
  ushort_t* w1T = (ushort_t*)(ws + alloc((size_t)NE * DIM * DIM * 2));
  ushort_t* w2T = (ushort_t*)(ws + alloc((size_t)NE * DIM * DIM * 2));
  ushort_t* H = (ushort_t*)(ws + alloc((size_t)RCAP * DIM * 2));

  hipMemsetAsync(ctrl, 0, 4096, stream);
  router_seq3<<<TOK / 32, 256, 0, stream>>>(tokens, rw, topi, topv);
  hist_kernel<<<TOK / 256, 256, 0, stream>>>(topi, ctrl);
  prefix_kernel<<<1, 64, 0, stream>>>(ctrl);
  init_rows<<<BMCAP / 256, 256, 0, stream>>>(row_token, row_gate);
  assign2<<<TOK / 256, 256, 0, stream>>>(topi, topv, ctrl, row_token,
                                         row_gate);
  cast_tokens<<<TOK * DIM / 8 / 256, 256, 0, stream>>>(tokens, X16);
  dim3 tg(16, 16, 8);
  transpose_cast<<<tg, 256, 0, stream>>>(w1, w1T);
  transpose_cast<<<tg, 256, 0, stream>>>(w2, w2T);
  // k=0 region: H then out-store; k=1 region: H then out-RMW (no atomics)
  dgemm<0, 0><<<544, 512, 0, stream>>>(X16, w1T, row_token, row_gate, ctrl, 0,
                                       H, out);
  dgemm<1, 0><<<544, 512, 0, stream>>>(H, w2T, row_token, row_gate, ctrl, 0, H,
                                       out);
  dgemm<0, 0><<<544, 512, 0, stream>>>(X16, w1T, row_token, row_gate, ctrl, 1,
                                       H, out);
  dgemm<1, 1><<<544, 512, 0, stream>>>(H, w2T, row_token, row_gate, ctrl, 1, H,
                                       out);
}

// Round 18
// 694.440 us; speedup vs baseline: 1.4772x; 1.0518x over previous
//
#include <hip/hip_runtime.h>
#include <hip/hip_bf16.h>
#include <math.h>
#include <stdint.h>

#define TOK 32768
#define DIM 1024
#define NE 8
#define NSEG 16                      /* (k, expert) segments */
#define BMCAP (2 * TOK + NSEG * 256) /* 69632 row slots (segments padded to 256) */
#define RCAP (TOK + NE * 256)        /* 34816 rows per k-region cap */

#define C_CNT(s) ((s) * 16)
#define C_CUR(s) (256 + (s) * 16)
#define C_SEG(s) (512 + (s))

typedef __attribute__((ext_vector_type(8))) short bf16x8;
typedef __attribute__((ext_vector_type(4))) float f32x4;
typedef unsigned short ushort_t;

__device__ __forceinline__ unsigned short f2b(float x) {
  union { float f; unsigned u; } v; v.f = x;
  unsigned r = v.u + 0x7fffu + ((v.u >> 16) & 1u);
  return (unsigned short)(r >> 16);
}

__device__ __forceinline__ void async16(void* lds, const void* g) {
  auto* lp = (__attribute__((address_space(3))) uint32_t*)lds;
  auto* gp = (__attribute__((address_space(1))) uint32_t*)(const_cast<void*>(g));
  __builtin_amdgcn_global_load_lds(gp, lp, 16, 0, 0);
}

// ---- router v3 (no atomics): FROZEN sequential fmaf chain ------------------
__global__ __launch_bounds__(256) void router_seq3(
    const float* __restrict__ tokens, const float* __restrict__ rw,
    int* __restrict__ topi, float* __restrict__ topv) {
  __shared__ float xs[2][32][132];
  __shared__ float wsh[2][8][132];
  __shared__ float sc[256];
  const int tid = threadIdx.x;
  const int e = tid & 7;
  const int tr = tid >> 3;
  const int t0 = blockIdx.x * 32;

  float4 lx0, lx1, lx2, lx3, lw;
  auto issue = [&](int c) {
    const int col = (tid & 31) * 4;
    lx0 = *(const float4*)&tokens[(size_t)(t0 + ((tid + 0) >> 5)) * DIM + c * 128 + col];
    lx1 = *(const float4*)&tokens[(size_t)(t0 + ((tid + 256) >> 5)) * DIM + c * 128 + col];
    lx2 = *(const float4*)&tokens[(size_t)(t0 + ((tid + 512) >> 5)) * DIM + c * 128 + col];
    lx3 = *(const float4*)&tokens[(size_t)(t0 + ((tid + 768) >> 5)) * DIM + c * 128 + col];
    lw  = *(const float4*)&rw[(size_t)(tid >> 5) * DIM + c * 128 + col];
  };
  auto commit = [&](int b) {
    const int col = (tid & 31) * 4;
    *(float4*)&xs[b][(tid + 0) >> 5][col] = lx0;
    *(float4*)&xs[b][(tid + 256) >> 5][col] = lx1;
    *(float4*)&xs[b][(tid + 512) >> 5][col] = lx2;
    *(float4*)&xs[b][(tid + 768) >> 5][col] = lx3;
    *(float4*)&wsh[b][tid >> 5][col] = lw;
  };

  issue(0);
  commit(0);
  __syncthreads();
  float s = 0.f;
  for (int c = 0; c < 8; c++) {
    const int b = c & 1;
    if (c + 1 < 8) issue(c + 1);
#pragma unroll
    for (int k4 = 0; k4 < 32; k4++) {
      const float4 xv = *(const float4*)&xs[b][tr][k4 * 4];
      const float4 wv = *(const float4*)&wsh[b][e][k4 * 4];
      s = fmaf(xv.x, wv.x, s);
      s = fmaf(xv.y, wv.y, s);
      s = fmaf(xv.z, wv.z, s);
      s = fmaf(xv.w, wv.w, s);
    }
    if (c + 1 < 8) commit(b ^ 1);
    __syncthreads();
  }
  sc[tid] = s;
  __syncthreads();
  if (e == 0) {
    float p[NE];
    float m = sc[tr * 8];
#pragma unroll
    for (int i = 1; i < NE; i++) m = fmaxf(m, sc[tr * 8 + i]);
    float sum = 0.f;
#pragma unroll
    for (int i = 0; i < NE; i++) {
      p[i] = expf(sc[tr * 8 + i] - m);
      sum += p[i];
    }
#pragma unroll
    for (int i = 0; i < NE; i++) p[i] = p[i] / sum;
    const int t = t0 + tr;
    int e0 = 0;
#pragma unroll
    for (int i = 1; i < NE; i++) if (p[i] > p[e0]) e0 = i;
    int e1 = (e0 == 0) ? 1 : 0;
#pragma unroll
    for (int i = 0; i < NE; i++) if (i != e0 && p[i] > p[e1]) e1 = i;
    topi[t * 2] = e0;     topv[t * 2] = p[e0];
    topi[t * 2 + 1] = e1; topv[t * 2 + 1] = p[e1];
  }
}

// ---- per-(k,expert) counts -------------------------------------------------
__global__ __launch_bounds__(256) void hist_kernel(const int* __restrict__ topi,
                                                   int* __restrict__ ctrl) {
  __shared__ int h[NSEG];
  const int tid = threadIdx.x;
  if (tid < NSEG) h[tid] = 0;
  __syncthreads();
  const int t = blockIdx.x * 256 + tid;
  atomicAdd(&h[topi[t * 2]], 1);
  atomicAdd(&h[8 + topi[t * 2 + 1]], 1);
  __syncthreads();
  if (tid < NSEG) atomicAdd(&ctrl[C_CNT(tid)], h[tid]);
}

__global__ void prefix_kernel(int* ctrl) {
  if (threadIdx.x == 0 && blockIdx.x == 0) {
    int s = 0;
    for (int g = 0; g < NSEG; g++) {
      ctrl[C_SEG(g)] = s;
      ctrl[C_CUR(g)] = s;
      s += (ctrl[C_CNT(g)] + 255) & ~255; /* pad segments to 256 (BM) */
    }
    ctrl[C_SEG(NSEG)] = s;
  }
}

__global__ __launch_bounds__(256) void init_rows(
    int* __restrict__ row_token, float* __restrict__ row_gate) {
  const int i = blockIdx.x * 256 + threadIdx.x;
  if (i < BMCAP) { row_token[i] = TOK; row_gate[i] = 0.f; }
}

__global__ __launch_bounds__(256) void assign2(
    const int* __restrict__ topi, const float* __restrict__ topv,
    int* __restrict__ ctrl, int* __restrict__ row_token,
    float* __restrict__ row_gate) {
  __shared__ int h[NSEG];
  __shared__ int base[NSEG];
  const int tid = threadIdx.x;
  const int t = blockIdx.x * 256 + tid;
  if (tid < NSEG) h[tid] = 0;
  __syncthreads();
  const int s0 = topi[t * 2], s1 = 8 + topi[t * 2 + 1];
  const int o0 = atomicAdd(&h[s0], 1);
  const int o1 = atomicAdd(&h[s1], 1);
  __syncthreads();
  if (tid < NSEG) base[tid] = atomicAdd(&ctrl[C_CUR(tid)], h[tid]);
  __syncthreads();
  const int p0 = base[s0] + o0, p1 = base[s1] + o1;
  row_token[p0] = t; row_gate[p0] = topv[t * 2];
  row_token[p1] = t; row_gate[p1] = topv[t * 2 + 1];
}

__global__ __launch_bounds__(256) void cast_tokens(
    const float* __restrict__ t, ushort_t* __restrict__ x16) {
  const size_t i = ((size_t)blockIdx.x * 256 + threadIdx.x) * 8;
  const float4 a = *(const float4*)(t + i);
  const float4 b = *(const float4*)(t + i + 4);
  bf16x8 h;
  h[0] = (short)f2b(a.x); h[1] = (short)f2b(a.y);
  h[2] = (short)f2b(a.z); h[3] = (short)f2b(a.w);
  h[4] = (short)f2b(b.x); h[5] = (short)f2b(b.y);
  h[6] = (short)f2b(b.z); h[7] = (short)f2b(b.w);
  *(bf16x8*)(x16 + i) = h;
}

__global__ __launch_bounds__(256) void transpose_cast(
    const float* __restrict__ w, ushort_t* __restrict__ wT) {
  __shared__ float tile[64][65];
  const int e = blockIdx.z;
  const int n0 = blockIdx.x * 64, k0 = blockIdx.y * 64;
  const int tx = threadIdx.x & 63, ty = threadIdx.x >> 6;
  const float* src = w + ((size_t)e << 20);
  ushort_t* dst = wT + ((size_t)e << 20);
#pragma unroll
  for (int r = ty; r < 64; r += 4)
    tile[r][tx] = src[(size_t)(k0 + r) * DIM + n0 + tx];
  __syncthreads();
#pragma unroll
  for (int r = ty; r < 64; r += 4)
    dst[(size_t)(n0 + r) * DIM + k0 + tx] = f2b(tile[tx][r]);
}

// --- grouped GEMM: 256x256, BK=64, 8 waves, dbuf+swizzle (r15-verified) -----
// PASS 0 (one dispatch, ALL 16 segments): H[rr,:] = gelu(X @ w1T[e]^T)
// PASS 1 (per k-region): out[tok,:] =/+= g * (H[rr,:] @ w2T[e]^T)
// H indexed by GLOBAL row slot rr.
template <int PASS, int ADD>
__global__ __launch_bounds__(512, 2) void dgemm(
    const ushort_t* __restrict__ Asrc, const ushort_t* __restrict__ Wt,
    const int* __restrict__ row_token, const float* __restrict__ row_gate,
    const int* __restrict__ ctrl, int s_lo, int s_hi, int nchunk,
    ushort_t* __restrict__ Hout, float* __restrict__ out) {
  const int l = (blockIdx.x & 7) * nchunk + (blockIdx.x >> 3);
  const int mt = l >> 2, nt = l & 3;
  const int rbase0 = ctrl[C_SEG(s_lo)];
  const int rend = ctrl[C_SEG(s_hi)];
  const int m0 = rbase0 + mt * 256;
  if (m0 >= rend) return;
  const int n0 = nt * 256;
  int sg = s_lo;
#pragma unroll
  for (int i = 0; i < NSEG - 1; i++)
    if (i + 1 < s_hi && i + 1 > s_lo && m0 >= ctrl[C_SEG(i + 1)] ? false : false) {}
  // segment search (wave-uniform):
  for (int i = s_lo + 1; i < s_hi; i++)
    if (m0 >= ctrl[C_SEG(i)]) sg = i;
  const int e = sg & 7;
  const ushort_t* B = Wt + ((size_t)e << 20);

  __shared__ __align__(16) char smem[131072];
  ushort_t (*As)[16384] = (ushort_t(*)[16384])smem;            // 2 x 32 KB
  ushort_t (*Bs)[16384] = (ushort_t(*)[16384])(smem + 65536);  // 2 x 32 KB
  float* scratch = (float*)smem; // epilogue: per-wave 4096 f32

  const int tid = threadIdx.x;
  const int lane = tid & 63;
  const int wave = tid >> 6;
  const int wm = wave >> 2, wn = wave & 3; // per-wave 128x64 output
  const int lr = lane & 15;
  const int lk = (lane >> 4) << 3;
  const int sx = (lr & 7) << 3;

  const int srow = tid >> 3;
  const int ko = (((tid & 7) ^ (srow & 7)) << 3); // pre-swizzled source col
  const ushort_t* asrc[4];
  const ushort_t* bsrc[4];
#pragma unroll
  for (int j = 0; j < 4; j++) {
    const int rA = j * 64 + srow;
    if (PASS == 0) {
      int tk = row_token[m0 + rA];
      if (tk >= TOK) tk = 0;
      asrc[j] = Asrc + (size_t)tk * DIM + ko;
    } else {
      asrc[j] = Asrc + (size_t)(m0 + rA) * DIM + ko;
    }
    bsrc[j] = B + (size_t)(n0 + rA) * DIM + ko;
  }
  const int ldst = (tid & ~63) * 8;

  f32x4 acc[8][4] = {};

  auto stage = [&](int b, int k0) {
#pragma unroll
    for (int j = 0; j < 4; j++) async16(&As[b][j * 4096 + ldst], asrc[j] + k0);
#pragma unroll
    for (int j = 0; j < 4; j++) async16(&Bs[b][j * 4096 + ldst], bsrc[j] + k0);
  };
  auto compute = [&](int b) {
#pragma unroll
    for (int kk = 0; kk < 2; kk++) {
      const int kc = (kk * 32 + lk) ^ sx;
      bf16x8 a[8], bb[4];
#pragma unroll
      for (int i = 0; i < 8; i++)
        a[i] = *(const bf16x8*)&As[b][(wm * 128 + i * 16 + lr) * 64 + kc];
#pragma unroll
      for (int i = 0; i < 4; i++)
        bb[i] = *(const bf16x8*)&Bs[b][(wn * 64 + i * 16 + lr) * 64 + kc];
#pragma unroll
      for (int mi = 0; mi < 8; mi++)
#pragma unroll
        for (int ni = 0; ni < 4; ni++)
          acc[mi][ni] = __builtin_amdgcn_mfma_f32_16x16x32_bf16(
              a[mi], bb[ni], acc[mi][ni], 0, 0, 0);
    }
  };

  stage(0, 0);
  __syncthreads();
  int cur = 0;
#pragma unroll 1
  for (int t = 0; t < 15; t++) {
    stage(cur ^ 1, (t + 1) * 64);
    compute(cur);
    __syncthreads();
    cur ^= 1;
  }
  compute(cur);
  __syncthreads(); // all waves done with As/Bs before scratch reuse

  // ---- LDS-transpose epilogue (r15-verified) ------------------------------
  const int grow = (lane >> 4) << 2;
  float* sw = scratch + wave * 4096;
#pragma unroll
  for (int half = 0; half < 2; half++) {
#pragma unroll
    for (int mi2 = 0; mi2 < 4; mi2++) {
      const int mi = half * 4 + mi2;
#pragma unroll
      for (int ni = 0; ni < 4; ni++) {
#pragma unroll
        for (int r = 0; r < 4; r++) {
          const int lrow = mi2 * 16 + grow + r;
          const int lcol = (ni * 16 + lr) ^ (((lrow >> 2) & 3) << 4);
          sw[lrow * 64 + lcol] = acc[mi][ni][r];
        }
      }
    }
    if (PASS == 0) {
#pragma unroll
      for (int i = 0; i < 8; i++) {
        const int lrow = i * 8 + (lane >> 3);
        const int q = ((lrow >> 2) & 3) << 4;
        const int c0 = (lane & 7) * 8;
        const f32x4 v0 = *(const f32x4*)&sw[lrow * 64 + (c0 ^ q)];
        const f32x4 v1 = *(const f32x4*)&sw[lrow * 64 + ((c0 + 4) ^ q)];
        bf16x8 h;
#pragma unroll
        for (int j = 0; j < 4; j++) {
          const float x = v0[j];
          h[j] = (short)f2b(0.5f * x * (1.f + erff(x * 0.70710678118654752f)));
        }
#pragma unroll
        for (int j = 0; j < 4; j++) {
          const float x = v1[j];
          h[4 + j] =
              (short)f2b(0.5f * x * (1.f + erff(x * 0.70710678118654752f)));
        }
        const int rr = m0 + wm * 128 + half * 64 + lrow;
        *(bf16x8*)&Hout[(size_t)rr * DIM + n0 + wn * 64 + c0] = h;
      }
    } else {
#pragma unroll
      for (int i = 0; i < 16; i++) {
        const int lrow = i * 4 + (lane >> 4);
        const int q = ((lrow >> 2) & 3) << 4;
        const int c0 = (lane & 15) * 4;
        const f32x4 v = *(const f32x4*)&sw[lrow * 64 + (c0 ^ q)];
        const int rr = m0 + wm * 128 + half * 64 + lrow;
        const int tok = row_token[rr];
        if (tok < TOK) {
          const float g = row_gate[rr];
          float* op = out + (size_t)tok * DIM + n0 + wn * 64 + c0;
          f32x4 res;
          if (ADD) {
            const f32x4 old = *(const f32x4*)op;
#pragma unroll
            for (int j = 0; j < 4; j++) res[j] = old[j] + g * v[j];
          } else {
#pragma unroll
            for (int j = 0; j < 4; j++) res[j] = g * v[j];
          }
          *(f32x4*)op = res;
        }
      }
    }
  }
}

extern "C" void kernel_launch(void* const* d_in, const int* in_sizes, int n_in,
                              void* d_out, int out_size, void* d_ws,
                              size_t ws_size, hipStream_t stream) {
  (void)in_sizes; (void)n_in; (void)ws_size; (void)out_size;
  const float* tokens = (const float*)d_in[0];
  const float* rw = (const float*)d_in[1];
  const float* w1 = (const float*)d_in[2];
  const float* w2 = (const float*)d_in[3];
  float* out = (float*)d_out;

  char* ws = (char*)d_ws;
  size_t off = 0;
  auto alloc = [&](size_t b) {
    size_t o = off;
    off += (b + 255) & ~(size_t)255;
    return o;
  };
  int* ctrl = (int*)(ws + alloc(4096));
  int* topi = (int*)(ws + alloc((size_t)TOK * 2 * 4));
  float* topv = (float*)(ws + alloc((size_t)TOK * 2 * 4));
  int* row_token = (int*)(ws + alloc((size_t)BMCAP * 4));
  float* row_gate = (float*)(ws + alloc((size_t)BMCAP * 4));
  ushort_t* X16 = (ushort_t*)(ws + alloc((size_t)TOK * DIM * 2));
  ushort_t* w1T = (ushort_t*)(ws + alloc((size_t)NE * DIM * DIM * 2));
  ushort_t* w2T = (ushort_t*)(ws + alloc((size_t)NE * DIM * DIM * 2));
  ushort_t* H = (ushort_t*)(ws + alloc((size_t)BMCAP * DIM * 2)); // unified

  hipMemsetAsync(ctrl, 0, 4096, stream);
  router_seq3<<<TOK / 32, 256, 0, stream>>>(tokens, rw, topi, topv);
  hist_kernel<<<TOK / 256, 256, 0, stream>>>(topi, ctrl);
  prefix_kernel<<<1, 64, 0, stream>>>(ctrl);
  init_rows<<<BMCAP / 256, 256, 0, stream>>>(row_token, row_gate);
  assign2<<<TOK / 256, 256, 0, stream>>>(topi, topv, ctrl, row_token,
                                         row_gate);
  cast_tokens<<<TOK * DIM / 8 / 256, 256, 0, stream>>>(tokens, X16);
  dim3 tg(16, 16, 8);
  transpose_cast<<<tg, 256, 0, stream>>>(w1, w1T);
  transpose_cast<<<tg, 256, 0, stream>>>(w2, w2T);
  // pass-0: ONE dispatch over all 16 segments (1088 = 8*136 chunked)
  dgemm<0, 0><<<1088, 512, 0, stream>>>(X16, w1T, row_token, row_gate, ctrl, 0,
                                        NSEG, 136, H, out);
  // pass-1: k0 stores, k1 RMW (544 = 8*68 chunked each)
  dgemm<1, 0><<<544, 512, 0, stream>>>(H, w2T, row_token, row_gate, ctrl, 0, 8,
                                       68, H, out);
  dgemm<1, 1><<<544, 512, 0, stream>>>(H, w2T, row_token, row_gate, ctrl, 8,
                                       NSEG, 68, H, out);
}

// Round 19
// 632.320 us; speedup vs baseline: 1.6223x; 1.0982x over previous
//
#include <hip/hip_runtime.h>
#include <hip/hip_bf16.h>
#include <math.h>
#include <stdint.h>

#define TOK 32768
#define DIM 1024
#define NE 8
#define NSEG 16                      /* (k, expert) segments */
#define BMCAP (2 * TOK + NSEG * 256) /* 69632 row slots (segments padded to 256) */

#define C_CNT(s) ((s) * 16)
#define C_CUR(s) (256 + (s) * 16)
#define C_SEG(s) (512 + (s))

typedef __attribute__((ext_vector_type(8))) short bf16x8;
typedef __attribute__((ext_vector_type(4))) float f32x4;
typedef unsigned short ushort_t;

__device__ __forceinline__ unsigned short f2b(float x) {
  union { float f; unsigned u; } v; v.f = x;
  unsigned r = v.u + 0x7fffu + ((v.u >> 16) & 1u);
  return (unsigned short)(r >> 16);
}

__device__ __forceinline__ void async16(void* lds, const void* g) {
  auto* lp = (__attribute__((address_space(3))) uint32_t*)lds;
  auto* gp = (__attribute__((address_space(1))) uint32_t*)(const_cast<void*>(g));
  __builtin_amdgcn_global_load_lds(gp, lp, 16, 0, 0);
}

// ---- router v3 (no atomics): FROZEN sequential fmaf chain ------------------
__global__ __launch_bounds__(256) void router_seq3(
    const float* __restrict__ tokens, const float* __restrict__ rw,
    int* __restrict__ topi, float* __restrict__ topv) {
  __shared__ float xs[2][32][132];
  __shared__ float wsh[2][8][132];
  __shared__ float sc[256];
  const int tid = threadIdx.x;
  const int e = tid & 7;
  const int tr = tid >> 3;
  const int t0 = blockIdx.x * 32;

  float4 lx0, lx1, lx2, lx3, lw;
  auto issue = [&](int c) {
    const int col = (tid & 31) * 4;
    lx0 = *(const float4*)&tokens[(size_t)(t0 + ((tid + 0) >> 5)) * DIM + c * 128 + col];
    lx1 = *(const float4*)&tokens[(size_t)(t0 + ((tid + 256) >> 5)) * DIM + c * 128 + col];
    lx2 = *(const float4*)&tokens[(size_t)(t0 + ((tid + 512) >> 5)) * DIM + c * 128 + col];
    lx3 = *(const float4*)&tokens[(size_t)(t0 + ((tid + 768) >> 5)) * DIM + c * 128 + col];
    lw  = *(const float4*)&rw[(size_t)(tid >> 5) * DIM + c * 128 + col];
  };
  auto commit = [&](int b) {
    const int col = (tid & 31) * 4;
    *(float4*)&xs[b][(tid + 0) >> 5][col] = lx0;
    *(float4*)&xs[b][(tid + 256) >> 5][col] = lx1;
    *(float4*)&xs[b][(tid + 512) >> 5][col] = lx2;
    *(float4*)&xs[b][(tid + 768) >> 5][col] = lx3;
    *(float4*)&wsh[b][tid >> 5][col] = lw;
  };

  issue(0);
  commit(0);
  __syncthreads();
  float s = 0.f;
  for (int c = 0; c < 8; c++) {
    const int b = c & 1;
    if (c + 1 < 8) issue(c + 1);
#pragma unroll
    for (int k4 = 0; k4 < 32; k4++) {
      const float4 xv = *(const float4*)&xs[b][tr][k4 * 4];
      const float4 wv = *(const float4*)&wsh[b][e][k4 * 4];
      s = fmaf(xv.x, wv.x, s);
      s = fmaf(xv.y, wv.y, s);
      s = fmaf(xv.z, wv.z, s);
      s = fmaf(xv.w, wv.w, s);
    }
    if (c + 1 < 8) commit(b ^ 1);
    __syncthreads();
  }
  sc[tid] = s;
  __syncthreads();
  if (e == 0) {
    float p[NE];
    float m = sc[tr * 8];
#pragma unroll
    for (int i = 1; i < NE; i++) m = fmaxf(m, sc[tr * 8 + i]);
    float sum = 0.f;
#pragma unroll
    for (int i = 0; i < NE; i++) {
      p[i] = expf(sc[tr * 8 + i] - m);
      sum += p[i];
    }
#pragma unroll
    for (int i = 0; i < NE; i++) p[i] = p[i] / sum;
    const int t = t0 + tr;
    int e0 = 0;
#pragma unroll
    for (int i = 1; i < NE; i++) if (p[i] > p[e0]) e0 = i;
    int e1 = (e0 == 0) ? 1 : 0;
#pragma unroll
    for (int i = 0; i < NE; i++) if (i != e0 && p[i] > p[e1]) e1 = i;
    topi[t * 2] = e0;     topv[t * 2] = p[e0];
    topi[t * 2 + 1] = e1; topv[t * 2 + 1] = p[e1];
  }
}

// ---- per-(k,expert) counts -------------------------------------------------
__global__ __launch_bounds__(256) void hist_kernel(const int* __restrict__ topi,
                                                   int* __restrict__ ctrl) {
  __shared__ int h[NSEG];
  const int tid = threadIdx.x;
  if (tid < NSEG) h[tid] = 0;
  __syncthreads();
  const int t = blockIdx.x * 256 + tid;
  atomicAdd(&h[topi[t * 2]], 1);
  atomicAdd(&h[8 + topi[t * 2 + 1]], 1);
  __syncthreads();
  if (tid < NSEG) atomicAdd(&ctrl[C_CNT(tid)], h[tid]);
}

__global__ void prefix_kernel(int* ctrl) {
  if (threadIdx.x == 0 && blockIdx.x == 0) {
    int s = 0;
    for (int g = 0; g < NSEG; g++) {
      ctrl[C_SEG(g)] = s;
      ctrl[C_CUR(g)] = s;
      s += (ctrl[C_CNT(g)] + 255) & ~255; /* pad segments to 256 (BM) */
    }
    ctrl[C_SEG(NSEG)] = s;
  }
}

__global__ __launch_bounds__(256) void init_rows(
    int* __restrict__ row_token, float* __restrict__ row_gate) {
  const int i = blockIdx.x * 256 + threadIdx.x;
  if (i < BMCAP) { row_token[i] = TOK; row_gate[i] = 0.f; }
}

__global__ __launch_bounds__(256) void assign2(
    const int* __restrict__ topi, const float* __restrict__ topv,
    int* __restrict__ ctrl, int* __restrict__ row_token,
    float* __restrict__ row_gate) {
  __shared__ int h[NSEG];
  __shared__ int base[NSEG];
  const int tid = threadIdx.x;
  const int t = blockIdx.x * 256 + tid;
  if (tid < NSEG) h[tid] = 0;
  __syncthreads();
  const int s0 = topi[t * 2], s1 = 8 + topi[t * 2 + 1];
  const int o0 = atomicAdd(&h[s0], 1);
  const int o1 = atomicAdd(&h[s1], 1);
  __syncthreads();
  if (tid < NSEG) base[tid] = atomicAdd(&ctrl[C_CUR(tid)], h[tid]);
  __syncthreads();
  const int p0 = base[s0] + o0, p1 = base[s1] + o1;
  row_token[p0] = t; row_gate[p0] = topv[t * 2];
  row_token[p1] = t; row_gate[p1] = topv[t * 2 + 1];
}

__global__ __launch_bounds__(256) void cast_tokens(
    const float* __restrict__ t, ushort_t* __restrict__ x16) {
  const size_t i = ((size_t)blockIdx.x * 256 + threadIdx.x) * 8;
  const float4 a = *(const float4*)(t + i);
  const float4 b = *(const float4*)(t + i + 4);
  bf16x8 h;
  h[0] = (short)f2b(a.x); h[1] = (short)f2b(a.y);
  h[2] = (short)f2b(a.z); h[3] = (short)f2b(a.w);
  h[4] = (short)f2b(b.x); h[5] = (short)f2b(b.y);
  h[6] = (short)f2b(b.z); h[7] = (short)f2b(b.w);
  *(bf16x8*)(x16 + i) = h;
}

__global__ __launch_bounds__(256) void transpose_cast(
    const float* __restrict__ w, ushort_t* __restrict__ wT) {
  __shared__ float tile[64][65];
  const int e = blockIdx.z;
  const int n0 = blockIdx.x * 64, k0 = blockIdx.y * 64;
  const int tx = threadIdx.x & 63, ty = threadIdx.x >> 6;
  const float* src = w + ((size_t)e << 20);
  ushort_t* dst = wT + ((size_t)e << 20);
#pragma unroll
  for (int r = ty; r < 64; r += 4)
    tile[r][tx] = src[(size_t)(k0 + r) * DIM + n0 + tx];
  __syncthreads();
#pragma unroll
  for (int r = ty; r < 64; r += 4)
    dst[(size_t)(n0 + r) * DIM + k0 + tx] = f2b(tile[tx][r]);
}

// --- grouped GEMM: 256x128 tile, BK=32, 8 waves, dbuf, 2 blocks/CU ----------
// Per-wave 64x64 output (acc=64 regs) -> launch_bounds(512,4) caps 128 VGPR;
// LDS 48KB -> 2 blocks/CU resident (16 waves/CU, cross-block barrier overlap).
// Swizzle: granule ^= (row&3)^((row>>2)&3), both-sides (rule #21).
// Epilogue: 4 cross-wave rounds through 32KB scratch, coalesced wide stores.
template <int PASS, int ADD>
__global__ __launch_bounds__(512, 4) void dgemm(
    const ushort_t* __restrict__ Asrc, const ushort_t* __restrict__ Wt,
    const int* __restrict__ row_token, const float* __restrict__ row_gate,
    const int* __restrict__ ctrl, int s_lo, int s_hi, int chunk,
    ushort_t* __restrict__ Hout, float* __restrict__ out) {
  const int l = (blockIdx.x & 7) * chunk + (blockIdx.x >> 3);
  const int mt = l >> 3, nt = l & 7; // n-fastest: 8 blocks share an A-panel
  const int rbase0 = ctrl[C_SEG(s_lo)];
  const int rend = ctrl[C_SEG(s_hi)];
  const int m0 = rbase0 + mt * 256;
  if (m0 >= rend) return;
  const int n0 = nt * 128;
  int sg = s_lo;
  for (int i = s_lo + 1; i < s_hi; i++)
    if (m0 >= ctrl[C_SEG(i)]) sg = i;
  const int e = sg & 7;
  const ushort_t* B = Wt + ((size_t)e << 20);

  __shared__ __align__(16) char smem[49152];
  ushort_t (*As)[8192] = (ushort_t(*)[8192])smem;           // 2 x 16 KB
  ushort_t (*Bs)[4096] = (ushort_t(*)[4096])(smem + 32768); // 2 x 8 KB
  float* scratch = (float*)smem; // epilogue: 64x128 f32 = 32 KB

  const int tid = threadIdx.x;
  const int lane = tid & 63;
  const int wave = tid >> 6;
  const int wm = wave >> 1, wn = wave & 1; // per-wave 64x64 output
  const int lr = lane & 15;
  // read-side physical granule XOR (element offset, <<3 = *8 elems)
  const int kx = (((lane >> 4) ^ (lr & 3) ^ ((lr >> 2) & 3)) << 3);

  // staging: A rows w*32+(l>>2) (+16 for j=1), B rows w*16+(l>>2);
  // source col granule = (l&3)^((l>>2)&3)^((l>>4)&3)  (both-sides involution)
  const int ko = (((lane & 3) ^ ((lane >> 2) & 3) ^ ((lane >> 4) & 3)) << 3);
  const int ar0 = wave * 32 + (lane >> 2);
  const int brr = wave * 16 + (lane >> 2);
  const ushort_t *asrc0, *asrc1, *bsrc;
  if (PASS == 0) {
    int tk0 = row_token[m0 + ar0];
    int tk1 = row_token[m0 + ar0 + 16];
    if (tk0 >= TOK) tk0 = 0;
    if (tk1 >= TOK) tk1 = 0;
    asrc0 = Asrc + (size_t)tk0 * DIM + ko;
    asrc1 = Asrc + (size_t)tk1 * DIM + ko;
  } else {
    asrc0 = Asrc + (size_t)(m0 + ar0) * DIM + ko;
    asrc1 = Asrc + (size_t)(m0 + ar0 + 16) * DIM + ko;
  }
  bsrc = B + (size_t)(n0 + brr) * DIM + ko;

  f32x4 acc[4][4] = {};

  auto stage = [&](int b, int k0) {
    async16(&As[b][wave * 1024], asrc0 + k0);
    async16(&As[b][wave * 1024 + 512], asrc1 + k0);
    async16(&Bs[b][wave * 512], bsrc + k0);
  };
  auto compute = [&](int b) {
    bf16x8 a[4], bb[4];
#pragma unroll
    for (int mi = 0; mi < 4; mi++)
      a[mi] = *(const bf16x8*)&As[b][(wm * 64 + mi * 16 + lr) * 32 + kx];
#pragma unroll
    for (int ni = 0; ni < 4; ni++)
      bb[ni] = *(const bf16x8*)&Bs[b][(wn * 64 + ni * 16 + lr) * 32 + kx];
#pragma unroll
    for (int mi = 0; mi < 4; mi++)
#pragma unroll
      for (int ni = 0; ni < 4; ni++)
        acc[mi][ni] = __builtin_amdgcn_mfma_f32_16x16x32_bf16(
            a[mi], bb[ni], acc[mi][ni], 0, 0, 0);
  };

  stage(0, 0);
  __syncthreads();
  int cur = 0;
#pragma unroll 1
  for (int t = 0; t < 31; t++) {
    stage(cur ^ 1, (t + 1) * 32);
    compute(cur);
    __syncthreads();
    cur ^= 1;
  }
  compute(cur);
  __syncthreads(); // K-loop done; smem becomes scratch

  // ---- epilogue: 4 rounds (one 64-row m-block each) -----------------------
  const int grow = (lane >> 4) << 2;
  const int erow = tid >> 3;       // 0..63
  const int ec0 = (tid & 7) * 16;  // col base, 16 cols/thread
#pragma unroll 1
  for (int rnd = 0; rnd < 4; rnd++) {
    if (wm == rnd) {
#pragma unroll
      for (int mi = 0; mi < 4; mi++) {
#pragma unroll
        for (int ni = 0; ni < 4; ni++) {
#pragma unroll
          for (int r = 0; r < 4; r++) {
            const int lrow = mi * 16 + grow + r;
            const int lcol = (wn * 64 + ni * 16 + lr) ^ ((lrow & 3) << 2);
            scratch[lrow * 128 + lcol] = acc[mi][ni][r];
          }
        }
      }
    }
    __syncthreads();
    {
      const int q = (erow & 3) << 2;
      f32x4 v[4];
#pragma unroll
      for (int k = 0; k < 4; k++)
        v[k] = *(const f32x4*)&scratch[erow * 128 + ((ec0 + 4 * k) ^ q)];
      const int rr = m0 + rnd * 64 + erow;
      if (PASS == 0) {
        bf16x8 h0, h1;
#pragma unroll
        for (int k = 0; k < 2; k++)
#pragma unroll
          for (int j = 0; j < 4; j++) {
            const float x = v[k][j];
            h0[k * 4 + j] =
                (short)f2b(0.5f * x * (1.f + erff(x * 0.70710678118654752f)));
          }
#pragma unroll
        for (int k = 0; k < 2; k++)
#pragma unroll
          for (int j = 0; j < 4; j++) {
            const float x = v[2 + k][j];
            h1[k * 4 + j] =
                (short)f2b(0.5f * x * (1.f + erff(x * 0.70710678118654752f)));
          }
        *(bf16x8*)&Hout[(size_t)rr * DIM + n0 + ec0] = h0;
        *(bf16x8*)&Hout[(size_t)rr * DIM + n0 + ec0 + 8] = h1;
      } else {
        const int tok = row_token[rr];
        if (tok < TOK) {
          const float g = row_gate[rr];
          float* op = out + (size_t)tok * DIM + n0 + ec0;
#pragma unroll
          for (int k = 0; k < 4; k++) {
            f32x4 res;
            if (ADD) {
              const f32x4 old = *(const f32x4*)(op + 4 * k);
#pragma unroll
              for (int j = 0; j < 4; j++) res[j] = old[j] + g * v[k][j];
            } else {
#pragma unroll
              for (int j = 0; j < 4; j++) res[j] = g * v[k][j];
            }
            *(f32x4*)(op + 4 * k) = res;
          }
        }
      }
    }
    __syncthreads();
  }
}

extern "C" void kernel_launch(void* const* d_in, const int* in_sizes, int n_in,
                              void* d_out, int out_size, void* d_ws,
                              size_t ws_size, hipStream_t stream) {
  (void)in_sizes; (void)n_in; (void)ws_size; (void)out_size;
  const float* tokens = (const float*)d_in[0];
  const float* rw = (const float*)d_in[1];
  const float* w1 = (const float*)d_in[2];
  const float* w2 = (const float*)d_in[3];
  float* out = (float*)d_out;

  char* ws = (char*)d_ws;
  size_t off = 0;
  auto alloc = [&](size_t b) {
    size_t o = off;
    off += (b + 255) & ~(size_t)255;
    return o;
  };
  int* ctrl = (int*)(ws + alloc(4096));
  int* topi = (int*)(ws + alloc((size_t)TOK * 2 * 4));
  float* topv = (float*)(ws + alloc((size_t)TOK * 2 * 4));
  int* row_token = (int*)(ws + alloc((size_t)BMCAP * 4));
  float* row_gate = (float*)(ws + alloc((size_t)BMCAP * 4));
  ushort_t* X16 = (ushort_t*)(ws + alloc((size_t)TOK * DIM * 2));
  ushort_t* w1T = (ushort_t*)(ws + alloc((size_t)NE * DIM * DIM * 2));
  ushort_t* w2T = (ushort_t*)(ws + alloc((size_t)NE * DIM * DIM * 2));
  ushort_t* H = (ushort_t*)(ws + alloc((size_t)BMCAP * DIM * 2)); // unified

  hipMemsetAsync(ctrl, 0, 4096, stream);
  router_seq3<<<TOK / 32, 256, 0, stream>>>(tokens, rw, topi, topv);
  hist_kernel<<<TOK / 256, 256, 0, stream>>>(topi, ctrl);
  prefix_kernel<<<1, 64, 0, stream>>>(ctrl);
  init_rows<<<BMCAP / 256, 256, 0, stream>>>(row_token, row_gate);
  assign2<<<TOK / 256, 256, 0, stream>>>(topi, topv, ctrl, row_token,
                                         row_gate);
  cast_tokens<<<TOK * DIM / 8 / 256, 256, 0, stream>>>(tokens, X16);
  dim3 tg(16, 16, 8);
  transpose_cast<<<tg, 256, 0, stream>>>(w1, w1T);
  transpose_cast<<<tg, 256, 0, stream>>>(w2, w2T);
  // pass-0 merged: all 16 segments, 272 m-tiles x 8 n-tiles = 2176 blocks
  dgemm<0, 0><<<2176, 512, 0, stream>>>(X16, w1T, row_token, row_gate, ctrl, 0,
                                        NSEG, 272, H, out);
  // pass-1: k0 stores, k1 RMW (136 m-tiles x 8 n-tiles = 1088 blocks each)
  dgemm<1, 0><<<1088, 512, 0, stream>>>(H, w2T, row_token, row_gate, ctrl, 0,
                                        8, 136, H, out);
  dgemm<1, 1><<<1088, 512, 0, stream>>>(H, w2T, row_token, row_gate, ctrl, 8,
                                        NSEG, 136, H, out);
}